// Round 1
// baseline (404.136 us; speedup 1.0000x reference)
//
#include <hip/hip_runtime.h>

// CrossAttention with KV length 1: softmax over size-1 axis == 1, so Q/K are
// dead. out[b,n,:] = (freq[b] @ Wv.T + bv) @ Wo.T + bo, broadcast over n.
//
// Round 8: R7's broadcast (fill-style, verified) kept verbatim; ONE change —
// the two GEMV stages (V = freq@Wv.T+bv, O2 = V@Wo.T+bo) are fused into a
// single kernel with a per-batch arrive/spin barrier. Grid (16,48) = 768
// blocks x 256 threads, far below the ~2048-block residency capacity (no LDS,
// low VGPR), so all blocks are co-resident and the spin cannot deadlock.
// Batch b's stage-2 begins as soon as its own 48 stage-1 blocks have
// published V[b,:] — per-batch pipelining instead of a global kernel
// boundary + full-device drain.

#define B_   16
#define N_   4096
#define CSP  768
#define CFD  512

// Fused: stage 1 computes V[b,j] (split-K, 16 lanes/output, shfl_xor reduce),
// publishes with device-scope release; stage 2 computes O2[b,c] after the
// per-batch counter reaches 48.
__global__ void __launch_bounds__(256) compute_vo2(
    const float* __restrict__ freq,   // [B, CFD]
    const float* __restrict__ Wv,     // [CSP, CFD]
    const float* __restrict__ bv,     // [CSP]
    const float* __restrict__ Wo,     // [CSP, CSP]
    const float* __restrict__ bo,     // [CSP]
    float* __restrict__ V,            // [B, CSP] (ws)
    float* __restrict__ O2,           // [B, CSP] (ws)
    unsigned* __restrict__ cnt)       // [B] zeroed per launch
{
    const int b = blockIdx.x;
    const int t = threadIdx.x;
    const int g = t >> 4;              // output within block (0..15)
    const int k = t & 15;              // k-slice lane (0..15)
    const int j = blockIdx.y * 16 + g; // channel (0..767)

    // ---- stage 1: V[b,j] = bv[j] + dot(freq[b,:], Wv[j,:]) ----
    {
        const float4* wr = (const float4*)(Wv + (size_t)j * CFD);
        const float4* fr = (const float4*)(freq + (size_t)b * CFD);
        float acc = 0.f;
#pragma unroll
        for (int i = 0; i < CFD / 4 / 16; ++i) {   // 8 iterations
            float4 w = wr[k + 16 * i];
            float4 f = fr[k + 16 * i];
            acc += w.x * f.x + w.y * f.y + w.z * f.z + w.w * f.w;
        }
#pragma unroll
        for (int m = 8; m >= 1; m >>= 1)
            acc += __shfl_xor(acc, m);
        if (k == 0) V[(size_t)b * CSP + j] = acc + bv[j];
    }

    // ---- publish + per-batch arrive/wait ----
    __syncthreads();                    // all 16 V-writes of this block done
    if (t == 0) {
        __threadfence();                // device-scope release of V writes
        atomicAdd(&cnt[b], 1u);         // arrive (device scope by default)
        while (__hip_atomic_load(&cnt[b], __ATOMIC_ACQUIRE,
                                 __HIP_MEMORY_SCOPE_AGENT) < 48u) {
            __builtin_amdgcn_s_sleep(1);
        }
        __threadfence();                // acquire: invalidate L1 before reads
    }
    __syncthreads();

    // ---- stage 2: O2[b,c] = bo[c] + dot(V[b,:], Wo[c,:]) ----
    {
        const int c = j;
        const float4* wr = (const float4*)(Wo + (size_t)c * CSP);
        const float4* vr = (const float4*)(V + (size_t)b * CSP);
        float acc = 0.f;
#pragma unroll
        for (int i = 0; i < CSP / 4 / 16; ++i) {   // 12 iterations
            float4 w = wr[k + 16 * i];
            float4 v = vr[k + 16 * i];
            acc += w.x * v.x + w.y * v.y + w.z * v.z + w.w * v.w;
        }
#pragma unroll
        for (int m = 8; m >= 1; m >>= 1)
            acc += __shfl_xor(acc, m);
        if (k == 0) O2[(size_t)b * CSP + c] = acc + bo[c];
    }
}

// Fill-style broadcast, out[b,n,:] = O2[b,:]. Verbatim from R7 (verified at
// ~fill speed). grid 4096, block 192 (3 waves); block k: b = k>>8, rows
// y0, y0+256, ..., y0+3840; thread t holds float4 col t of O2[b] in one
// register; each iteration stores one contiguous 3 KB row.
__global__ void __launch_bounds__(192) broadcast_out(
    const float* __restrict__ O2,     // [B, CSP]
    float* __restrict__ out)          // [B, N, CSP]
{
    const int k  = blockIdx.x;        // 0..4095
    const int b  = k >> 8;            // 256 blocks per batch
    const int y0 = k & 255;
    const int t  = threadIdx.x;       // 0..191

    const float4 v = ((const float4*)(O2 + (size_t)b * CSP))[t];

    float4* dst = (float4*)(out + ((size_t)b * N_ + (size_t)y0) * CSP) + t;
#pragma unroll
    for (int i = 0; i < 16; ++i) {
        dst[(size_t)i * 256 * (CSP / 4)] = v;    // stride 256 rows = 768 KB
    }
}

extern "C" void kernel_launch(void* const* d_in, const int* in_sizes, int n_in,
                              void* d_out, int out_size, void* d_ws, size_t ws_size,
                              hipStream_t stream) {
    // Inputs (setup_inputs order):
    // 0: spatial_tokens (dead)  1: freq_token [B,CFD]
    // 2: Wq (dead) 3: bq (dead) 4: Wk (dead) 5: bk (dead)
    // 6: Wv [CSP,CFD] 7: bv [CSP] 8: Wo [CSP,CSP] 9: bo [CSP]
    const float* freq = (const float*)d_in[1];
    const float* Wv   = (const float*)d_in[6];
    const float* bv   = (const float*)d_in[7];
    const float* Wo   = (const float*)d_in[8];
    const float* bo   = (const float*)d_in[9];
    float* out = (float*)d_out;

    float* V  = (float*)d_ws;            // [B, CSP]
    float* O2 = V + (size_t)B_ * CSP;    // [B, CSP]
    unsigned* cnt = (unsigned*)(O2 + (size_t)B_ * CSP);  // [B_], 64 B

    // ws is poisoned by the harness each iteration -> counters must be zeroed.
    hipMemsetAsync(cnt, 0, B_ * sizeof(unsigned), stream);

    compute_vo2<<<dim3(B_, CSP / 16), 256, 0, stream>>>(freq, Wv, bv, Wo, bo,
                                                        V, O2, cnt);
    broadcast_out<<<dim3(4096), 192, 0, stream>>>(O2, out);
}

// Round 2
// 315.316 us; speedup vs baseline: 1.2817x; 1.2817x over previous
//
#include <hip/hip_runtime.h>
#include <hip/hip_bf16.h>

// CrossAttention with KV length 1: softmax over size-1 axis == 1, so Q/K are
// dead. out[b,n,:] = (freq[b] @ Wv.T + bv) @ Wo.T + bo, broadcast over n.
//
// Round 9: REVERT to the verified R7 three-kernel structure (314.9 us).
// R8's fused spin-barrier variant regressed +89 us: 768 device-scope
// atomics + spin-loads on a single 64 B line ping-pong across 8 XCD L2s,
// and the fix targeted a gap worth <=10 us. Keeping the kernel-boundary
// drain as the (cheap) inter-stage sync.

#define B_   16
#define N_   4096
#define CSP  768
#define CFD  512

// Kernel 1: V[b,j] = bv[j] + dot(freq[b,:], Wv[j,:])
// grid (16, 48), block 256. 16 outputs/block; 16 lanes per output; split-K
// with shfl_xor reduce (all loads independent -> one latency round-trip).
__global__ void __launch_bounds__(256) compute_v(const float* __restrict__ freq,
                                                 const float* __restrict__ Wv,
                                                 const float* __restrict__ bv,
                                                 float* __restrict__ V) {
    const int b = blockIdx.x;
    const int t = threadIdx.x;
    const int g = t >> 4;              // output within block (0..15)
    const int k = t & 15;              // k-slice lane (0..15)
    const int j = blockIdx.y * 16 + g; // output channel (0..767)

    const float4* wr = (const float4*)(Wv + (size_t)j * CFD);
    const float4* fr = (const float4*)(freq + (size_t)b * CFD);

    float acc = 0.f;
#pragma unroll
    for (int i = 0; i < CFD / 4 / 16; ++i) {       // 8 iterations
        float4 w = wr[k + 16 * i];
        float4 f = fr[k + 16 * i];
        acc += w.x * f.x + w.y * f.y + w.z * f.z + w.w * f.w;
    }
#pragma unroll
    for (int m = 8; m >= 1; m >>= 1)
        acc += __shfl_xor(acc, m);
    if (k == 0) V[(size_t)b * CSP + j] = acc + bv[j];
}

// Kernel 2: O2[b,c] = bo[c] + dot(V[b,:], Wo[c,:])  — same split-K layout.
__global__ void __launch_bounds__(256) compute_o2(const float* __restrict__ V,
                                                  const float* __restrict__ Wo,
                                                  const float* __restrict__ bo,
                                                  float* __restrict__ O2) {
    const int b = blockIdx.x;
    const int t = threadIdx.x;
    const int g = t >> 4;
    const int k = t & 15;
    const int c = blockIdx.y * 16 + g;

    const float4* wr = (const float4*)(Wo + (size_t)c * CSP);
    const float4* vr = (const float4*)(V + (size_t)b * CSP);

    float acc = 0.f;
#pragma unroll
    for (int i = 0; i < CSP / 4 / 16; ++i) {       // 12 iterations
        float4 w = wr[k + 16 * i];
        float4 v = vr[k + 16 * i];
        acc += w.x * v.x + w.y * v.y + w.z * v.z + w.w * v.w;
    }
#pragma unroll
    for (int m = 8; m >= 1; m >>= 1)
        acc += __shfl_xor(acc, m);
    if (k == 0) O2[(size_t)b * CSP + c] = acc + bo[c];
}

// Kernel 3: fill-style broadcast, out[b,n,:] = O2[b,:].
// grid 4096, block 192 (3 waves). Block k: batch b = k>>8, row offset
// y0 = k&255; writes rows y0, y0+256, ..., y0+3840 (16 rows). Thread t holds
// the single float4 col t of O2[b] in one register; each iteration the block
// stores one contiguous 3 KB row (192 x 16 B), consecutive blocks cover
// consecutive rows.
__global__ void __launch_bounds__(192) broadcast_out(
    const float* __restrict__ O2,     // [B, CSP]
    float* __restrict__ out)          // [B, N, CSP]
{
    const int k  = blockIdx.x;        // 0..4095
    const int b  = k >> 8;            // 256 blocks per batch
    const int y0 = k & 255;
    const int t  = threadIdx.x;       // 0..191

    const float4 v = ((const float4*)(O2 + (size_t)b * CSP))[t];

    float4* dst = (float4*)(out + ((size_t)b * N_ + (size_t)y0) * CSP) + t;
#pragma unroll
    for (int i = 0; i < 16; ++i) {
        dst[(size_t)i * 256 * (CSP / 4)] = v;    // stride 256 rows = 768 KB
    }
}

extern "C" void kernel_launch(void* const* d_in, const int* in_sizes, int n_in,
                              void* d_out, int out_size, void* d_ws, size_t ws_size,
                              hipStream_t stream) {
    // Inputs (setup_inputs order):
    // 0: spatial_tokens (dead)  1: freq_token [B,CFD]
    // 2: Wq (dead) 3: bq (dead) 4: Wk (dead) 5: bk (dead)
    // 6: Wv [CSP,CFD] 7: bv [CSP] 8: Wo [CSP,CSP] 9: bo [CSP]
    const float* freq = (const float*)d_in[1];
    const float* Wv   = (const float*)d_in[6];
    const float* bv   = (const float*)d_in[7];
    const float* Wo   = (const float*)d_in[8];
    const float* bo   = (const float*)d_in[9];
    float* out = (float*)d_out;

    float* V  = (float*)d_ws;            // [B, CSP]
    float* O2 = V + (size_t)B_ * CSP;    // [B, CSP]

    compute_v <<<dim3(B_, CSP / 16), 256, 0, stream>>>(freq, Wv, bv, V);
    compute_o2<<<dim3(B_, CSP / 16), 256, 0, stream>>>(V, Wo, bo, O2);
    broadcast_out<<<dim3(4096), 192, 0, stream>>>(O2, out);
}